// Round 1
// baseline (8691.254 us; speedup 1.0000x reference)
//
#include <hip/hip_runtime.h>
#include <math.h>

#define L_ 2
#define D_ 1024
#define H_ 16
#define HD_ 64
#define DFF_ 4096
#define V_ 32000
#define T_ 2
#define B_ 2
#define S_ 1024
#define BS_ (B_*S_)
#define D3_ (3*D_)
#define VC_ 8000   // vocab chunk (125 * 64)

// out[i] = base[i] + lam0*d[i] + lam1*d[i+n]
__global__ void merge_kernel(const float* __restrict__ base, const float* __restrict__ dlt,
                             const float* __restrict__ lam, float* __restrict__ out, int n) {
    float l0 = lam[0], l1 = lam[1];
    for (int i = blockIdx.x * blockDim.x + threadIdx.x; i < n; i += gridDim.x * blockDim.x)
        out[i] = base[i] + l0 * dlt[i] + l1 * dlt[i + n];
}

__global__ void embed_kernel(const int* __restrict__ ids, const float* __restrict__ embm,
                             float* __restrict__ x) {
    int row = blockIdx.x;
    int id = ids[row];
    const float4* src = (const float4*)(embm + (size_t)id * D_);
    float4* dst = (float4*)(x + (size_t)row * D_);
    for (int d = threadIdx.x; d < D_ / 4; d += blockDim.x) dst[d] = src[d];
}

// one block (256 thr) per row; out = (x-mu)*rsqrt(var+eps)*g
__global__ __launch_bounds__(256) void ln_kernel(const float* __restrict__ x,
                                                 const float* __restrict__ g,
                                                 float* __restrict__ out) {
    __shared__ float sred[8];
    int row = blockIdx.x;
    const float* xr = x + (size_t)row * D_;
    float s = 0.f, ss = 0.f;
    for (int d = threadIdx.x; d < D_; d += 256) { float v = xr[d]; s += v; ss += v * v; }
    for (int o = 32; o > 0; o >>= 1) { s += __shfl_down(s, o); ss += __shfl_down(ss, o); }
    int lane = threadIdx.x & 63, wid = threadIdx.x >> 6;
    if (lane == 0) { sred[wid] = s; sred[4 + wid] = ss; }
    __syncthreads();
    if (threadIdx.x == 0) {
        sred[0] = sred[0] + sred[1] + sred[2] + sred[3];
        sred[4] = sred[4] + sred[5] + sred[6] + sred[7];
    }
    __syncthreads();
    float mu = sred[0] * (1.0f / D_);
    float var = sred[4] * (1.0f / D_) - mu * mu;
    float r = rsqrtf(var + 1e-5f);
    float* orow = out + (size_t)row * D_;
    for (int d = threadIdx.x; d < D_; d += 256) orow[d] = (xr[d] - mu) * r * g[d];
}

// C[M,N] = A[M,K] @ B  (BT: B is N x K row-major, i.e. A @ B^T)
// ADDR: C = R + A@B.  GELU: tanh-approx gelu on result.
// Tiles: 64x64, BK=16, 256 threads, 4x4 per thread.
template<int BT, int ADDR, int GELU>
__global__ __launch_bounds__(256) void gemm_kernel(const float* __restrict__ A,
                                                   const float* __restrict__ B,
                                                   const float* __restrict__ R,
                                                   float* __restrict__ C,
                                                   int M, int N, int K) {
    __shared__ float As[16][68];
    __shared__ float Bs[16][68];
    int bm = blockIdx.y * 64, bn = blockIdx.x * 64;
    int tid = threadIdx.x;
    int tn = tid & 15, tm = tid >> 4;
    float acc[4][4] = {};
    for (int k0 = 0; k0 < K; k0 += 16) {
        #pragma unroll
        for (int e = tid; e < 1024; e += 256) {
            int m = e >> 4, k = e & 15;
            As[k][m] = A[(size_t)(bm + m) * K + k0 + k];
        }
        if (BT) {
            #pragma unroll
            for (int e = tid; e < 1024; e += 256) {
                int n = e >> 4, k = e & 15;
                Bs[k][n] = B[(size_t)(bn + n) * K + k0 + k];
            }
        } else {
            #pragma unroll
            for (int e = tid; e < 1024; e += 256) {
                int k = e >> 6, n = e & 63;
                Bs[k][n] = B[(size_t)(k0 + k) * N + bn + n];
            }
        }
        __syncthreads();
        #pragma unroll
        for (int k = 0; k < 16; k++) {
            float4 av = *(const float4*)&As[k][tm * 4];
            float4 bv = *(const float4*)&Bs[k][tn * 4];
            float aa[4] = {av.x, av.y, av.z, av.w};
            float bb[4] = {bv.x, bv.y, bv.z, bv.w};
            #pragma unroll
            for (int i = 0; i < 4; i++)
                #pragma unroll
                for (int j = 0; j < 4; j++) acc[i][j] += aa[i] * bb[j];
        }
        __syncthreads();
    }
    #pragma unroll
    for (int i = 0; i < 4; i++) {
        int m = bm + tm * 4 + i;
        #pragma unroll
        for (int j = 0; j < 4; j++) {
            int n = bn + tn * 4 + j;
            float v = acc[i][j];
            if (ADDR) v += R[(size_t)m * N + n];
            if (GELU) {
                float u = v;
                float c = 0.7978845608028654f * (u + 0.044715f * u * u * u);
                v = 0.5f * u * (1.0f + tanhf(c));
            }
            C[(size_t)m * N + n] = v;
        }
    }
}

// fused causal attention, one block per (b,h,q) row.
// qkv layout (B*S, 3D): q at [h*64], k at [D + h*64], v at [2D + h*64]
__global__ __launch_bounds__(256) void attn_kernel(const float* __restrict__ qkv,
                                                   float* __restrict__ out) {
    int q = blockIdx.x, h = blockIdx.y, b = blockIdx.z;
    int tid = threadIdx.x;
    __shared__ float qv[HD_];
    __shared__ float sc[S_];
    __shared__ float sred[8];
    __shared__ float op[4][HD_];
    size_t rowq = (size_t)(b * S_ + q) * D3_;
    if (tid < HD_) qv[tid] = qkv[rowq + h * HD_ + tid];
    __syncthreads();
    int kn = q + 1;
    for (int k = tid; k < kn; k += 256) {
        const float* kr = qkv + (size_t)(b * S_ + k) * D3_ + D_ + h * HD_;
        float s = 0.f;
        #pragma unroll
        for (int d = 0; d < HD_; d++) s += qv[d] * kr[d];
        sc[k] = s * 0.125f; // 1/sqrt(64)
    }
    __syncthreads();
    float m = -1e30f;
    for (int k = tid; k < kn; k += 256) m = fmaxf(m, sc[k]);
    for (int o = 32; o > 0; o >>= 1) m = fmaxf(m, __shfl_down(m, o));
    int lane = tid & 63, wid = tid >> 6;
    if (lane == 0) sred[wid] = m;
    __syncthreads();
    if (tid == 0) sred[0] = fmaxf(fmaxf(sred[0], sred[1]), fmaxf(sred[2], sred[3]));
    __syncthreads();
    m = sred[0];
    float l = 0.f;
    for (int k = tid; k < kn; k += 256) { float p = __expf(sc[k] - m); sc[k] = p; l += p; }
    for (int o = 32; o > 0; o >>= 1) l += __shfl_down(l, o);
    if (lane == 0) sred[4 + wid] = l;
    __syncthreads();
    if (tid == 0) sred[4] = sred[4] + sred[5] + sred[6] + sred[7];
    __syncthreads();
    l = sred[4];
    int d = tid & 63, c = tid >> 6;
    float acc = 0.f;
    for (int k = c; k < kn; k += 4)
        acc += sc[k] * qkv[(size_t)(b * S_ + k) * D3_ + 2 * D_ + h * HD_ + d];
    op[c][d] = acc;
    __syncthreads();
    if (tid < HD_) {
        float o_ = (op[0][tid] + op[1][tid] + op[2][tid] + op[3][tid]) / l;
        out[(size_t)(b * S_ + q) * D_ + h * HD_ + tid] = o_;
    }
}

__global__ void loss_init_kernel(float* rm, float* rl, float* rtl) {
    int i = blockIdx.x * blockDim.x + threadIdx.x;
    if (i < BS_) { rm[i] = -1e30f; rl[i] = 0.f; rtl[i] = 0.f; }
}

// one block per row; online logsumexp update over this vocab chunk + target capture
__global__ __launch_bounds__(256) void loss_chunk_kernel(const float* __restrict__ lg,
                                                         const int* __restrict__ labels,
                                                         float* rm, float* rl, float* rtl,
                                                         int v0) {
    int row = blockIdx.x;
    const float* lr = lg + (size_t)row * VC_;
    int tid = threadIdx.x;
    __shared__ float sred[8];
    float m = -1e30f;
    for (int j = tid; j < VC_; j += 256) m = fmaxf(m, lr[j]);
    for (int o = 32; o > 0; o >>= 1) m = fmaxf(m, __shfl_down(m, o));
    int lane = tid & 63, wid = tid >> 6;
    if (lane == 0) sred[wid] = m;
    __syncthreads();
    if (tid == 0) sred[0] = fmaxf(fmaxf(sred[0], sred[1]), fmaxf(sred[2], sred[3]));
    __syncthreads();
    float cm = sred[0];
    float s = 0.f;
    for (int j = tid; j < VC_; j += 256) s += __expf(lr[j] - cm);
    for (int o = 32; o > 0; o >>= 1) s += __shfl_down(s, o);
    if (lane == 0) sred[4 + wid] = s;
    __syncthreads();
    if (tid == 0) {
        float cs = sred[4] + sred[5] + sred[6] + sred[7];
        float om = rm[row], ol = rl[row];
        float nm = fmaxf(om, cm);
        rl[row] = ol * __expf(om - nm) + cs * __expf(cm - nm);
        rm[row] = nm;
        int b = row / S_, spos = row % S_;
        if (spos < S_ - 1) {
            int tgt = labels[b * S_ + spos + 1];
            if (tgt >= v0 && tgt < v0 + VC_) rtl[row] = lr[tgt - v0];
        }
    }
}

__global__ __launch_bounds__(256) void loss_final_kernel(const float* rm, const float* rl,
                                                         const float* rtl, float* out) {
    __shared__ float sred[4];
    float s = 0.f;
    for (int row = threadIdx.x; row < BS_; row += 256) {
        int spos = row % S_;
        if (spos < S_ - 1) s += (rm[row] + logf(rl[row])) - rtl[row];
    }
    for (int o = 32; o > 0; o >>= 1) s += __shfl_down(s, o);
    int lane = threadIdx.x & 63, wid = threadIdx.x >> 6;
    if (lane == 0) sred[wid] = s;
    __syncthreads();
    if (threadIdx.x == 0)
        out[0] = (sred[0] + sred[1] + sred[2] + sred[3]) * (1.0f / (B_ * (S_ - 1)));
}

extern "C" void kernel_launch(void* const* d_in, const int* in_sizes, int n_in,
                              void* d_out, int out_size, void* d_ws, size_t ws_size,
                              hipStream_t stream) {
    const int*   ids    = (const int*)d_in[0];
    const int*   labels = (const int*)d_in[1];
    const float* lam    = (const float*)d_in[2];
    const float* emb    = (const float*)d_in[3];
    const float* Wqkv   = (const float*)d_in[4];
    const float* Wo     = (const float*)d_in[5];
    const float* W1     = (const float*)d_in[6];
    const float* W2     = (const float*)d_in[7];
    const float* g1     = (const float*)d_in[8];
    const float* g2     = (const float*)d_in[9];
    const float* gf     = (const float*)d_in[10];
    const float* dEmb   = (const float*)d_in[11];
    const float* dWqkv  = (const float*)d_in[12];
    const float* dWo    = (const float*)d_in[13];
    const float* dW1    = (const float*)d_in[14];
    const float* dW2    = (const float*)d_in[15];
    const float* dG1    = (const float*)d_in[16];
    const float* dG2    = (const float*)d_in[17];
    const float* dGf    = (const float*)d_in[18];
    float* out = (float*)d_out;
    float* ws  = (float*)d_ws;

    size_t off = 0;
    auto alloc = [&](size_t n) { float* p = ws + off; off += n; return p; };
    float* emb_m  = alloc((size_t)V_ * D_);          // 32.77M
    float* Wqkv_m = alloc((size_t)L_ * D_ * D3_);    // 6.29M
    float* Wo_m   = alloc((size_t)L_ * D_ * D_);     // 2.10M
    float* W1_m   = alloc((size_t)L_ * D_ * DFF_);   // 8.39M
    float* W2_m   = alloc((size_t)L_ * DFF_ * D_);   // 8.39M
    float* g1_m   = alloc(L_ * D_);
    float* g2_m   = alloc(L_ * D_);
    float* gf_m   = alloc(D_);
    float* h      = alloc((size_t)BS_ * D_);         // 2.10M
    float* a      = alloc((size_t)BS_ * D_);         // 2.10M
    float* qkv    = alloc((size_t)BS_ * D3_);        // 6.29M
    float* attno  = alloc((size_t)BS_ * D_);         // 2.10M
    float* ffh    = alloc((size_t)BS_ * DFF_);       // 8.39M
    float* rm     = alloc(BS_);
    float* rl     = alloc(BS_);
    float* rtl    = alloc(BS_);
    // logits chunk (BS_*VC_ = 16.38M floats) reuses qkv+attno+ffh (16.78M), dead by then
    float* lchunk = qkv;
    // total ws use: ~316 MB

    auto mgrid = [](size_t n) { size_t g = (n + 255) / 256; return (int)(g > 8192 ? 8192 : g); };

    // ---- weight merges ----
    merge_kernel<<<mgrid((size_t)V_ * D_), 256, 0, stream>>>(emb, dEmb, lam, emb_m, V_ * D_);
    merge_kernel<<<mgrid((size_t)L_ * D_ * D3_), 256, 0, stream>>>(Wqkv, dWqkv, lam, Wqkv_m, L_ * D_ * D3_);
    merge_kernel<<<mgrid((size_t)L_ * D_ * D_), 256, 0, stream>>>(Wo, dWo, lam, Wo_m, L_ * D_ * D_);
    merge_kernel<<<mgrid((size_t)L_ * D_ * DFF_), 256, 0, stream>>>(W1, dW1, lam, W1_m, L_ * D_ * DFF_);
    merge_kernel<<<mgrid((size_t)L_ * DFF_ * D_), 256, 0, stream>>>(W2, dW2, lam, W2_m, L_ * DFF_ * D_);
    merge_kernel<<<mgrid(L_ * D_), 256, 0, stream>>>(g1, dG1, lam, g1_m, L_ * D_);
    merge_kernel<<<mgrid(L_ * D_), 256, 0, stream>>>(g2, dG2, lam, g2_m, L_ * D_);
    merge_kernel<<<mgrid(D_), 256, 0, stream>>>(gf, dGf, lam, gf_m, D_);

    // ---- embedding ----
    embed_kernel<<<BS_, 256, 0, stream>>>(ids, emb_m, h);

    // ---- transformer layers ----
    for (int l = 0; l < L_; l++) {
        ln_kernel<<<BS_, 256, 0, stream>>>(h, g1_m + l * D_, a);
        gemm_kernel<0, 0, 0><<<dim3(D3_ / 64, BS_ / 64), 256, 0, stream>>>(
            a, Wqkv_m + (size_t)l * D_ * D3_, nullptr, qkv, BS_, D3_, D_);
        attn_kernel<<<dim3(S_, H_, B_), 256, 0, stream>>>(qkv, attno);
        gemm_kernel<0, 1, 0><<<dim3(D_ / 64, BS_ / 64), 256, 0, stream>>>(
            attno, Wo_m + (size_t)l * D_ * D_, h, h, BS_, D_, D_);
        ln_kernel<<<BS_, 256, 0, stream>>>(h, g2_m + l * D_, a);
        gemm_kernel<0, 0, 1><<<dim3(DFF_ / 64, BS_ / 64), 256, 0, stream>>>(
            a, W1_m + (size_t)l * D_ * DFF_, nullptr, ffh, BS_, DFF_, D_);
        gemm_kernel<0, 1, 0><<<dim3(D_ / 64, BS_ / 64), 256, 0, stream>>>(
            ffh, W2_m + (size_t)l * DFF_ * D_, h, h, BS_, D_, DFF_);
    }

    // ---- final LN ----
    ln_kernel<<<BS_, 256, 0, stream>>>(h, gf_m, a);

    // ---- logits + loss (chunked over vocab, online logsumexp) ----
    loss_init_kernel<<<(BS_ + 255) / 256, 256, 0, stream>>>(rm, rl, rtl);
    for (int c = 0; c < V_ / VC_; c++) {
        int v0 = c * VC_;
        gemm_kernel<1, 0, 0><<<dim3(VC_ / 64, BS_ / 64), 256, 0, stream>>>(
            a, emb_m + (size_t)v0 * D_, nullptr, lchunk, BS_, VC_, D_);
        loss_chunk_kernel<<<BS_, 256, 0, stream>>>(lchunk, labels, rm, rl, rtl, v0);
    }
    loss_final_kernel<<<1, 256, 0, stream>>>(rm, rl, rtl, out);
}

// Round 2
// 1803.940 us; speedup vs baseline: 4.8179x; 4.8179x over previous
//
#include <hip/hip_runtime.h>
#include <math.h>

#define L_ 2
#define D_ 1024
#define H_ 16
#define HD_ 64
#define DFF_ 4096
#define V_ 32000
#define B_ 2
#define S_ 1024
#define BS_ (B_*S_)
#define D3_ (3*D_)
#define VC_ 6400   // vocab chunk: 50 tiles of 128

typedef __attribute__((ext_vector_type(8))) short short8;
typedef __attribute__((ext_vector_type(4))) float f32x4;

__device__ __forceinline__ float b2f(unsigned short u) {
    return __uint_as_float(((unsigned int)u) << 16);
}
__device__ __forceinline__ unsigned short f2b(float f) {
    unsigned int u = __float_as_uint(f);
    return (unsigned short)((u + 0x7fffu + ((u >> 16) & 1u)) >> 16);
}
__device__ __forceinline__ float blo(unsigned int u) { return __uint_as_float(u << 16); }
__device__ __forceinline__ float bhi(unsigned int u) { return __uint_as_float(u & 0xffff0000u); }

__device__ __forceinline__ void gld16(const void* g, void* l) {
    __builtin_amdgcn_global_load_lds(
        (const __attribute__((address_space(1))) unsigned int*)g,
        (__attribute__((address_space(3))) unsigned int*)l, 16, 0, 0);
}

// ---------------- merges ----------------

// fp32 merge (small gammas): out[i] = base[i] + l0*d[i] + l1*d[i+tstride]
__global__ void merge_f32_kernel(const float* __restrict__ base, const float* __restrict__ dlt,
                                 size_t tstride, const float* __restrict__ lam,
                                 float* __restrict__ out, int n) {
    float l0 = lam[0], l1 = lam[1];
    for (int i = blockIdx.x * blockDim.x + threadIdx.x; i < n; i += gridDim.x * blockDim.x)
        out[i] = base[i] + l0 * dlt[i] + l1 * dlt[i + tstride];
}

// fp32 -> bf16 merge, no transpose (embedding). n4 = count of float4 groups.
__global__ void merge_bf16_kernel(const float* __restrict__ base, const float* __restrict__ dlt,
                                  size_t tstride, const float* __restrict__ lam,
                                  unsigned short* __restrict__ out, size_t n4) {
    float l0 = lam[0], l1 = lam[1];
    for (size_t q = blockIdx.x * blockDim.x + threadIdx.x; q < n4; q += (size_t)gridDim.x * blockDim.x) {
        size_t i = q * 4;
        float4 b = *(const float4*)(base + i);
        float4 d0 = *(const float4*)(dlt + i);
        float4 d1 = *(const float4*)(dlt + tstride + i);
        ushort4 o;
        o.x = f2b(b.x + l0 * d0.x + l1 * d1.x);
        o.y = f2b(b.y + l0 * d0.y + l1 * d1.y);
        o.z = f2b(b.z + l0 * d0.z + l1 * d1.z);
        o.w = f2b(b.w + l0 * d0.w + l1 * d1.w);
        *(ushort4*)(out + i) = o;
    }
}

// merge + transpose: in (K x N fp32), out (N x K bf16). 64x64 tiles.
__global__ __launch_bounds__(256) void mt_kernel(const float* __restrict__ in,
                                                 const float* __restrict__ din, size_t tstride,
                                                 const float* __restrict__ lam,
                                                 unsigned short* __restrict__ outT,
                                                 int K, int N) {
    __shared__ float T[64][65];
    float l0 = lam[0], l1 = lam[1];
    int n0 = blockIdx.x * 64, k0 = blockIdx.y * 64;
    int tr = threadIdx.x >> 4;   // 0..15
    int tc = threadIdx.x & 15;   // 0..15
    #pragma unroll
    for (int rep = 0; rep < 4; rep++) {
        int kk = tr + rep * 16;
        size_t idx = (size_t)(k0 + kk) * N + n0 + tc * 4;
        float4 b = *(const float4*)(in + idx);
        float4 d0 = *(const float4*)(din + idx);
        float4 d1 = *(const float4*)(din + tstride + idx);
        T[kk][tc * 4 + 0] = b.x + l0 * d0.x + l1 * d1.x;
        T[kk][tc * 4 + 1] = b.y + l0 * d0.y + l1 * d1.y;
        T[kk][tc * 4 + 2] = b.z + l0 * d0.z + l1 * d1.z;
        T[kk][tc * 4 + 3] = b.w + l0 * d0.w + l1 * d1.w;
    }
    __syncthreads();
    #pragma unroll
    for (int rep = 0; rep < 4; rep++) {
        int n = tr + rep * 16;
        int kc = tc * 4;
        ushort4 o;
        o.x = f2b(T[kc + 0][n]);
        o.y = f2b(T[kc + 1][n]);
        o.z = f2b(T[kc + 2][n]);
        o.w = f2b(T[kc + 3][n]);
        *(ushort4*)(outT + (size_t)(n0 + n) * K + k0 + kc) = o;
    }
}

// ---------------- embedding / LN ----------------

__global__ void embed_kernel(const int* __restrict__ ids, const unsigned short* __restrict__ embm,
                             float* __restrict__ h) {
    int row = blockIdx.x;
    int id = ids[row];
    const unsigned short* src = embm + (size_t)id * D_;
    float* dst = h + (size_t)row * D_;
    for (int d = threadIdx.x; d < D_; d += 256) dst[d] = b2f(src[d]);
}

// h fp32 in -> a bf16 out
__global__ __launch_bounds__(256) void ln_kernel(const float* __restrict__ x,
                                                 const float* __restrict__ g,
                                                 unsigned short* __restrict__ out) {
    __shared__ float sred[8];
    int row = blockIdx.x;
    const float* xr = x + (size_t)row * D_;
    float s = 0.f, ss = 0.f;
    for (int d = threadIdx.x; d < D_; d += 256) { float v = xr[d]; s += v; ss += v * v; }
    for (int o = 32; o > 0; o >>= 1) { s += __shfl_down(s, o); ss += __shfl_down(ss, o); }
    int lane = threadIdx.x & 63, wid = threadIdx.x >> 6;
    if (lane == 0) { sred[wid] = s; sred[4 + wid] = ss; }
    __syncthreads();
    if (threadIdx.x == 0) {
        sred[0] = sred[0] + sred[1] + sred[2] + sred[3];
        sred[4] = sred[4] + sred[5] + sred[6] + sred[7];
    }
    __syncthreads();
    float mu = sred[0] * (1.0f / D_);
    float var = sred[4] * (1.0f / D_) - mu * mu;
    float r = rsqrtf(var + 1e-5f);
    unsigned short* orow = out + (size_t)row * D_;
    for (int d = threadIdx.x; d < D_; d += 256) orow[d] = f2b((xr[d] - mu) * r * g[d]);
}

// ---------------- MFMA GEMM ----------------
// C[M,N] = A[M,K] @ Bt[N,K]^T, bf16 inputs, fp32 accum.
// MODE 0: Cf = acc (fp32). 1: Cf += acc (residual). 2: Cb = bf16(acc). 3: Cb = bf16(gelu(acc)).
// 128x128 tile, BK=32, 256 thr = 4 waves, wave does 64x64 via 4x4 MFMA 16x16x32 tiles.
template<int MODE>
__global__ __launch_bounds__(256) void gemm_mfma(const unsigned short* __restrict__ A,
                                                 const unsigned short* __restrict__ Bt,
                                                 float* __restrict__ Cf,
                                                 unsigned short* __restrict__ Cb,
                                                 int M, int N, int K) {
    __shared__ unsigned short As[128 * 32];
    __shared__ unsigned short Bs[128 * 32];
    int bm = blockIdx.y * 128, bn = blockIdx.x * 128;
    int tid = threadIdx.x;
    int w = tid >> 6, lane = tid & 63;
    int wm = (w & 1) * 64, wn = (w >> 1) * 64;
    int l15 = lane & 15, quad = lane >> 4;
    f32x4 acc[4][4] = {};

    int arow = w * 32 + (lane >> 2);
    int aseg = (lane & 3) * 8;
    const unsigned short* gA0 = A + (size_t)(bm + arow) * K + aseg;
    const unsigned short* gA1 = A + (size_t)(bm + arow + 16) * K + aseg;
    const unsigned short* gB0 = Bt + (size_t)(bn + arow) * K + aseg;
    const unsigned short* gB1 = Bt + (size_t)(bn + arow + 16) * K + aseg;
    unsigned short* lA0 = &As[arow * 32 + aseg];
    unsigned short* lA1 = &As[(arow + 16) * 32 + aseg];
    unsigned short* lB0 = &Bs[arow * 32 + aseg];
    unsigned short* lB1 = &Bs[(arow + 16) * 32 + aseg];

    for (int k0 = 0; k0 < K; k0 += 32) {
        gld16(gA0 + k0, lA0);
        gld16(gA1 + k0, lA1);
        gld16(gB0 + k0, lB0);
        gld16(gB1 + k0, lB1);
        __syncthreads();
        short8 af[4], bfm[4];
        #pragma unroll
        for (int i = 0; i < 4; i++) af[i] = *(const short8*)&As[(wm + i * 16 + l15) * 32 + quad * 8];
        #pragma unroll
        for (int j = 0; j < 4; j++) bfm[j] = *(const short8*)&Bs[(wn + j * 16 + l15) * 32 + quad * 8];
        #pragma unroll
        for (int i = 0; i < 4; i++)
            #pragma unroll
            for (int j = 0; j < 4; j++)
                acc[i][j] = __builtin_amdgcn_mfma_f32_16x16x32_bf16(af[i], bfm[j], acc[i][j], 0, 0, 0);
        __syncthreads();
    }

    #pragma unroll
    for (int i = 0; i < 4; i++) {
        int row = bm + wm + i * 16 + quad * 4;
        #pragma unroll
        for (int j = 0; j < 4; j++) {
            int col = bn + wn + j * 16 + l15;
            #pragma unroll
            for (int r = 0; r < 4; r++) {
                size_t idx = (size_t)(row + r) * N + col;
                float v = acc[i][j][r];
                if (MODE == 0) Cf[idx] = v;
                if (MODE == 1) Cf[idx] += v;
                if (MODE == 2) Cb[idx] = f2b(v);
                if (MODE == 3) {
                    float c = 0.7978845608028654f * (v + 0.044715f * v * v * v);
                    Cb[idx] = f2b(0.5f * v * (1.0f + tanhf(c)));
                }
            }
        }
    }
}

// ---------------- flash attention ----------------
// grid (qtiles=16, H, B), block 256. Q tile 64, K tiles of 64, online softmax.
#define UNPACK8(u, dst) { (dst)[0]=blo((u).x);(dst)[1]=bhi((u).x);(dst)[2]=blo((u).y);(dst)[3]=bhi((u).y);(dst)[4]=blo((u).z);(dst)[5]=bhi((u).z);(dst)[6]=blo((u).w);(dst)[7]=bhi((u).w); }

__global__ __launch_bounds__(256) void attn_kernel(const unsigned short* __restrict__ qkv,
                                                   unsigned short* __restrict__ attno) {
    int qt = blockIdx.x, h = blockIdx.y, b = blockIdx.z;
    int tid = threadIdx.x;
    int tq = tid >> 4, tk = tid & 15;
    __shared__ float Qs[64][68];
    __shared__ float Kt[64][68];          // Kt[d][k]
    __shared__ float Vs[64][68];
    __shared__ unsigned short Ps[64][68]; // P in bf16

    float o[4][4] = {};
    float m_i[4] = {-1e30f, -1e30f, -1e30f, -1e30f};
    float l_i[4] = {0.f, 0.f, 0.f, 0.f};

    int rr = tid >> 2, dseg = tid & 3, d0 = dseg * 16;

    // stage Q tile
    {
        const unsigned short* g = qkv + (size_t)(b * S_ + qt * 64 + rr) * D3_ + h * HD_ + d0;
        uint4 u0 = *(const uint4*)g;
        uint4 u1 = *(const uint4*)(g + 8);
        float* qd = &Qs[rr][d0];
        UNPACK8(u0, qd); UNPACK8(u1, qd + 8);
    }

    for (int kt = 0; kt <= qt; kt++) {
        __syncthreads();  // prev-iter reads done (and Q visible first iter)
        // stage K (transposed) and V
        {
            const unsigned short* g = qkv + (size_t)(b * S_ + kt * 64 + rr) * D3_ + h * HD_ + d0;
            uint4 ku0 = *(const uint4*)(g + D_);
            uint4 ku1 = *(const uint4*)(g + D_ + 8);
            uint4 vu0 = *(const uint4*)(g + 2 * D_);
            uint4 vu1 = *(const uint4*)(g + 2 * D_ + 8);
            float ktmp[16];
            UNPACK8(ku0, ktmp); UNPACK8(ku1, ktmp + 8);
            #pragma unroll
            for (int u = 0; u < 16; u++) Kt[d0 + u][rr] = ktmp[u];
            float* vd = &Vs[rr][d0];
            UNPACK8(vu0, vd); UNPACK8(vu1, vd + 8);
        }
        __syncthreads();

        // scores 64x64, thread computes 4x4
        float s[4][4] = {};
        for (int d = 0; d < 64; d++) {
            float4 kv = *(const float4*)&Kt[d][tk * 4];
            float q0 = Qs[tq * 4 + 0][d], q1 = Qs[tq * 4 + 1][d];
            float q2 = Qs[tq * 4 + 2][d], q3 = Qs[tq * 4 + 3][d];
            s[0][0] += q0 * kv.x; s[0][1] += q0 * kv.y; s[0][2] += q0 * kv.z; s[0][3] += q0 * kv.w;
            s[1][0] += q1 * kv.x; s[1][1] += q1 * kv.y; s[1][2] += q1 * kv.z; s[1][3] += q1 * kv.w;
            s[2][0] += q2 * kv.x; s[2][1] += q2 * kv.y; s[2][2] += q2 * kv.z; s[2][3] += q2 * kv.w;
            s[3][0] += q3 * kv.x; s[3][1] += q3 * kv.y; s[3][2] += q3 * kv.z; s[3][3] += q3 * kv.w;
        }
        #pragma unroll
        for (int i = 0; i < 4; i++)
            #pragma unroll
            for (int j = 0; j < 4; j++) {
                float v = s[i][j] * 0.125f;
                if (kt == qt && (tk * 4 + j) > (tq * 4 + i)) v = -1e30f;
                s[i][j] = v;
            }
        // online softmax per q-row (16-lane groups)
        #pragma unroll
        for (int i = 0; i < 4; i++) {
            float rm = fmaxf(fmaxf(s[i][0], s[i][1]), fmaxf(s[i][2], s[i][3]));
            for (int off = 1; off < 16; off <<= 1) rm = fmaxf(rm, __shfl_xor(rm, off));
            float mnew = fmaxf(m_i[i], rm);
            float alpha = __expf(m_i[i] - mnew);
            float lsum = 0.f;
            ushort4 pb;
            {
                float p0 = __expf(s[i][0] - mnew), p1 = __expf(s[i][1] - mnew);
                float p2 = __expf(s[i][2] - mnew), p3 = __expf(s[i][3] - mnew);
                lsum = p0 + p1 + p2 + p3;
                pb.x = f2b(p0); pb.y = f2b(p1); pb.z = f2b(p2); pb.w = f2b(p3);
            }
            for (int off = 1; off < 16; off <<= 1) lsum += __shfl_xor(lsum, off);
            l_i[i] = l_i[i] * alpha + lsum;
            m_i[i] = mnew;
            #pragma unroll
            for (int j = 0; j < 4; j++) o[i][j] *= alpha;
            *(ushort4*)&Ps[tq * 4 + i][tk * 4] = pb;
        }
        __syncthreads();
        // PV: o[i][j] += sum_k P[qi][k] * V[k][dj]
        for (int k = 0; k < 64; k++) {
            float4 vv = *(const float4*)&Vs[k][tk * 4];
            float p0 = b2f(Ps[tq * 4 + 0][k]);
            float p1 = b2f(Ps[tq * 4 + 1][k]);
            float p2 = b2f(Ps[tq * 4 + 2][k]);
            float p3 = b2f(Ps[tq * 4 + 3][k]);
            o[0][0] += p0 * vv.x; o[0][1] += p0 * vv.y; o[0][2] += p0 * vv.z; o[0][3] += p0 * vv.w;
            o[1][0] += p1 * vv.x; o[1][1] += p1 * vv.y; o[1][2] += p1 * vv.z; o[1][3] += p1 * vv.w;
            o[2][0] += p2 * vv.x; o[2][1] += p2 * vv.y; o[2][2] += p2 * vv.z; o[2][3] += p2 * vv.w;
            o[3][0] += p3 * vv.x; o[3][1] += p3 * vv.y; o[3][2] += p3 * vv.z; o[3][3] += p3 * vv.w;
        }
    }

    #pragma unroll
    for (int i = 0; i < 4; i++) {
        float inv = 1.0f / l_i[i];
        size_t row = (size_t)(b * S_ + qt * 64 + tq * 4 + i);
        #pragma unroll
        for (int j = 0; j < 4; j++)
            attno[row * D_ + h * HD_ + tk * 4 + j] = f2b(o[i][j] * inv);
    }
}

// ---------------- loss ----------------

__global__ void loss_init_kernel(float* rm, float* rl, float* rtl) {
    int i = blockIdx.x * blockDim.x + threadIdx.x;
    if (i < BS_) { rm[i] = -1e30f; rl[i] = 0.f; rtl[i] = 0.f; }
}

__global__ __launch_bounds__(256) void loss_chunk_kernel(const float* __restrict__ lg,
                                                         const int* __restrict__ labels,
                                                         float* rm, float* rl, float* rtl,
                                                         int v0) {
    int row = blockIdx.x;
    const float* lr = lg + (size_t)row * VC_;
    int tid = threadIdx.x;
    __shared__ float sred[8];
    float m = -1e30f;
    for (int j = tid; j < VC_; j += 256) m = fmaxf(m, lr[j]);
    for (int o = 32; o > 0; o >>= 1) m = fmaxf(m, __shfl_down(m, o));
    int lane = tid & 63, wid = tid >> 6;
    if (lane == 0) sred[wid] = m;
    __syncthreads();
    if (tid == 0) sred[0] = fmaxf(fmaxf(sred[0], sred[1]), fmaxf(sred[2], sred[3]));
    __syncthreads();
    float cm = sred[0];
    float s = 0.f;
    for (int j = tid; j < VC_; j += 256) s += __expf(lr[j] - cm);
    for (int o = 32; o > 0; o >>= 1) s += __shfl_down(s, o);
    if (lane == 0) sred[4 + wid] = s;
    __syncthreads();
    if (tid == 0) {
        float cs = sred[4] + sred[5] + sred[6] + sred[7];
        float om = rm[row], ol = rl[row];
        float nm = fmaxf(om, cm);
        rl[row] = ol * __expf(om - nm) + cs * __expf(cm - nm);
        rm[row] = nm;
        int b = row / S_, spos = row % S_;
        if (spos < S_ - 1) {
            int tgt = labels[b * S_ + spos + 1];
            if (tgt >= v0 && tgt < v0 + VC_) rtl[row] = lr[tgt - v0];
        }
    }
}

__global__ __launch_bounds__(256) void loss_final_kernel(const float* rm, const float* rl,
                                                         const float* rtl, float* out) {
    __shared__ float sred[4];
    float s = 0.f;
    for (int row = threadIdx.x; row < BS_; row += 256) {
        int spos = row % S_;
        if (spos < S_ - 1) s += (rm[row] + logf(rl[row])) - rtl[row];
    }
    for (int o = 32; o > 0; o >>= 1) s += __shfl_down(s, o);
    int lane = threadIdx.x & 63, wid = threadIdx.x >> 6;
    if (lane == 0) sred[wid] = s;
    __syncthreads();
    if (threadIdx.x == 0)
        out[0] = (sred[0] + sred[1] + sred[2] + sred[3]) * (1.0f / (B_ * (S_ - 1)));
}

// ---------------- launch ----------------

extern "C" void kernel_launch(void* const* d_in, const int* in_sizes, int n_in,
                              void* d_out, int out_size, void* d_ws, size_t ws_size,
                              hipStream_t stream) {
    const int*   ids    = (const int*)d_in[0];
    const int*   labels = (const int*)d_in[1];
    const float* lam    = (const float*)d_in[2];
    const float* emb    = (const float*)d_in[3];
    const float* Wqkv   = (const float*)d_in[4];
    const float* Wo     = (const float*)d_in[5];
    const float* W1     = (const float*)d_in[6];
    const float* W2     = (const float*)d_in[7];
    const float* g1     = (const float*)d_in[8];
    const float* g2     = (const float*)d_in[9];
    const float* gf     = (const float*)d_in[10];
    const float* dEmb   = (const float*)d_in[11];
    const float* dWqkv  = (const float*)d_in[12];
    const float* dWo    = (const float*)d_in[13];
    const float* dW1    = (const float*)d_in[14];
    const float* dW2    = (const float*)d_in[15];
    const float* dG1    = (const float*)d_in[16];
    const float* dG2    = (const float*)d_in[17];
    const float* dGf    = (const float*)d_in[18];
    float* out = (float*)d_out;

    char* wsb = (char*)d_ws;
    size_t off = 0;
    auto alloc = [&](size_t bytes) {
        off = (off + 255) & ~(size_t)255;
        void* p = wsb + off;
        off += bytes;
        return p;
    };
    unsigned short* embm  = (unsigned short*)alloc((size_t)V_ * D_ * 2);
    unsigned short* WqkvT = (unsigned short*)alloc((size_t)L_ * D3_ * D_ * 2);
    unsigned short* WoT   = (unsigned short*)alloc((size_t)L_ * D_ * D_ * 2);
    unsigned short* W1T   = (unsigned short*)alloc((size_t)L_ * DFF_ * D_ * 2);
    unsigned short* W2T   = (unsigned short*)alloc((size_t)L_ * D_ * DFF_ * 2);
    float* g1m = (float*)alloc((size_t)L_ * D_ * 4);
    float* g2m = (float*)alloc((size_t)L_ * D_ * 4);
    float* gfm = (float*)alloc((size_t)D_ * 4);
    float* h   = (float*)alloc((size_t)BS_ * D_ * 4);
    unsigned short* a_bf  = (unsigned short*)alloc((size_t)BS_ * D_ * 2);
    unsigned short* qkv   = (unsigned short*)alloc((size_t)BS_ * D3_ * 2);
    unsigned short* attno = (unsigned short*)alloc((size_t)BS_ * D_ * 2);
    unsigned short* ffh   = (unsigned short*)alloc((size_t)BS_ * DFF_ * 2);
    float* lchunk = (float*)alloc((size_t)BS_ * VC_ * 4);
    float* rm  = (float*)alloc(BS_ * 4);
    float* rl  = (float*)alloc(BS_ * 4);
    float* rtl = (float*)alloc(BS_ * 4);

    // ---- merges ----
    merge_bf16_kernel<<<4096, 256, 0, stream>>>(emb, dEmb, (size_t)V_ * D_, lam, embm, (size_t)V_ * D_ / 4);
    for (int l = 0; l < L_; l++) {
        mt_kernel<<<dim3(D3_ / 64, D_ / 64), 256, 0, stream>>>(
            Wqkv + (size_t)l * D_ * D3_, dWqkv + (size_t)l * D_ * D3_, (size_t)L_ * D_ * D3_,
            lam, WqkvT + (size_t)l * D3_ * D_, D_, D3_);
        mt_kernel<<<dim3(D_ / 64, D_ / 64), 256, 0, stream>>>(
            Wo + (size_t)l * D_ * D_, dWo + (size_t)l * D_ * D_, (size_t)L_ * D_ * D_,
            lam, WoT + (size_t)l * D_ * D_, D_, D_);
        mt_kernel<<<dim3(DFF_ / 64, D_ / 64), 256, 0, stream>>>(
            W1 + (size_t)l * D_ * DFF_, dW1 + (size_t)l * D_ * DFF_, (size_t)L_ * D_ * DFF_,
            lam, W1T + (size_t)l * DFF_ * D_, D_, DFF_);
        mt_kernel<<<dim3(D_ / 64, DFF_ / 64), 256, 0, stream>>>(
            W2 + (size_t)l * DFF_ * D_, dW2 + (size_t)l * DFF_ * D_, (size_t)L_ * DFF_ * D_,
            lam, W2T + (size_t)l * D_ * DFF_, DFF_, D_);
    }
    merge_f32_kernel<<<8, 256, 0, stream>>>(g1, dG1, (size_t)L_ * D_, lam, g1m, L_ * D_);
    merge_f32_kernel<<<8, 256, 0, stream>>>(g2, dG2, (size_t)L_ * D_, lam, g2m, L_ * D_);
    merge_f32_kernel<<<4, 256, 0, stream>>>(gf, dGf, (size_t)D_, lam, gfm, D_);

    // ---- embedding ----
    embed_kernel<<<BS_, 256, 0, stream>>>(ids, embm, h);

    // ---- layers ----
    for (int l = 0; l < L_; l++) {
        ln_kernel<<<BS_, 256, 0, stream>>>(h, g1m + l * D_, a_bf);
        gemm_mfma<2><<<dim3(D3_ / 128, BS_ / 128), 256, 0, stream>>>(
            a_bf, WqkvT + (size_t)l * D3_ * D_, nullptr, qkv, BS_, D3_, D_);
        attn_kernel<<<dim3(S_ / 64, H_, B_), 256, 0, stream>>>(qkv, attno);
        gemm_mfma<1><<<dim3(D_ / 128, BS_ / 128), 256, 0, stream>>>(
            attno, WoT + (size_t)l * D_ * D_, h, nullptr, BS_, D_, D_);
        ln_kernel<<<BS_, 256, 0, stream>>>(h, g2m + l * D_, a_bf);
        gemm_mfma<3><<<dim3(DFF_ / 128, BS_ / 128), 256, 0, stream>>>(
            a_bf, W1T + (size_t)l * DFF_ * D_, nullptr, ffh, BS_, DFF_, D_);
        gemm_mfma<1><<<dim3(D_ / 128, BS_ / 128), 256, 0, stream>>>(
            ffh, W2T + (size_t)l * D_ * DFF_, h, nullptr, BS_, D_, DFF_);
    }

    // ---- final LN ----
    ln_kernel<<<BS_, 256, 0, stream>>>(h, gfm, a_bf);

    // ---- logits + loss ----
    loss_init_kernel<<<(BS_ + 255) / 256, 256, 0, stream>>>(rm, rl, rtl);
    for (int c = 0; c < V_ / VC_; c++) {
        int v0 = c * VC_;
        gemm_mfma<0><<<dim3(VC_ / 128, BS_ / 128), 256, 0, stream>>>(
            a_bf, embm + (size_t)v0 * D_, lchunk, nullptr, BS_, VC_, D_);
        loss_chunk_kernel<<<BS_, 256, 0, stream>>>(lchunk, labels, rm, rl, rtl, v0);
    }
    loss_final_kernel<<<1, 256, 0, stream>>>(rm, rl, rtl, out);
}